// Round 1
// baseline (18387.033 us; speedup 1.0000x reference)
//
#include <hip/hip_runtime.h>

// Decoder scan: B=1024, T=128, M=256, P=256, 127 steps.
// Strategy: batch-parallel persistent scan kernel (1 wave = 1 batch, 4/wg),
// XW = X @ WU_dx^T precomputed once (bf16), per-step matvecs via MFMA 16x16x32
// with pre-swizzled bf16 weight fragments. c-state fp32 in LDS, h bf16.

#define B_SZ 1024
#define T_SZ 128
#define M_SZ 256
#define NSTEP 127

typedef __attribute__((ext_vector_type(8))) short short8;
typedef __attribute__((ext_vector_type(4))) float f32x4;

__device__ __forceinline__ float bf2f_lo(unsigned u) {
  return __builtin_bit_cast(float, u << 16);
}
__device__ __forceinline__ float bf2f_hi(unsigned u) {
  return __builtin_bit_cast(float, u & 0xffff0000u);
}
__device__ __forceinline__ unsigned short f2bf(float f) {
  unsigned u = __builtin_bit_cast(unsigned, f);
  u = (u + 0x7fffu + ((u >> 16) & 1u)) >> 16;  // RNE
  return (unsigned short)u;
}
__device__ __forceinline__ float fexp2(float x) { return __builtin_amdgcn_exp2f(x); }
__device__ __forceinline__ float frcp(float x) { return __builtin_amdgcn_rcpf(x); }
// tanh(x) = 1 - 2/(exp2(2x*log2e)+1)
__device__ __forceinline__ float tanh_f(float x) {
  float t = fexp2(x * 2.8853900817779268f);
  return 1.f - 2.f * frcp(t + 1.f);
}
__device__ __forceinline__ float sigm_f(float x) {
  return frcp(1.f + fexp2(x * -1.4426950408889634f));
}
__device__ __forceinline__ short8 as_s8(uint4 u) { return __builtin_bit_cast(short8, u); }

// ---------------- prep: weight bf16 fragment swizzles + bias sum ----------------
// B-frag layout for mfma_f32_16x16x32_bf16: lane holds B[k = (lane>>4)*8 + j][n = lane&15]
// W1F: WU_dd^T frags  (mt 0..15, ks 0..15)  dW = d @ WU_d[:, :512]^T
// W2F: W_hh^T frags   (jt 0..63, ks 0..7)   gates = h @ W_hh^T
// WxF: WU_dx^T frags  (mt 0..15, ks 0..7)   XW = X @ WU_d[:, 512:]^T
__global__ void prep_w(const float* __restrict__ WU_d,
                       const float* __restrict__ W_hh,
                       const float* __restrict__ b_ih,
                       const float* __restrict__ b_hh,
                       unsigned short* __restrict__ W1F,
                       unsigned short* __restrict__ W2F,
                       unsigned short* __restrict__ WxF,
                       float* __restrict__ bsum) {
  int i = blockIdx.x * 256 + threadIdx.x;
  if (i < 131072) {
    int j = i & 7, lane = (i >> 3) & 63, ks = (i >> 9) & 15, mt = i >> 13;
    int r = lane & 15, kg = lane >> 4;
    int k = ks * 32 + kg * 8 + j;
    W1F[i] = f2bf(WU_d[(mt * 16 + r) * 768 + k]);
  } else if (i < 131072 + 262144) {
    int i2 = i - 131072;
    int j = i2 & 7, lane = (i2 >> 3) & 63, ks = (i2 >> 9) & 7, jt = i2 >> 12;
    int r = lane & 15, kg = lane >> 4;
    int k = ks * 32 + kg * 8 + j;
    W2F[i2] = f2bf(W_hh[(jt * 16 + r) * 256 + k]);
  } else if (i < 131072 + 262144 + 65536) {
    int i3 = i - (131072 + 262144);
    int j = i3 & 7, lane = (i3 >> 3) & 63, ks = (i3 >> 9) & 7, mt = i3 >> 12;
    int r = lane & 15, kg = lane >> 4;
    int k = 512 + ks * 32 + kg * 8 + j;
    WxF[i3] = f2bf(WU_d[(mt * 16 + r) * 768 + k]);
  } else if (i < 131072 + 262144 + 65536 + 1024) {
    int i4 = i - (131072 + 262144 + 65536);
    bsum[i4] = b_ih[i4] + b_hh[i4];
  }
}

// ---------------- prep: XW[b][t][m] = sum_k X[t][b][k] * WU_dx[m][k], + Xbf copy ----------------
// One block per b. MFMA: A = X[b] (128t x 256k), B = WxF frags, D -> XW (bf16).
__global__ __launch_bounds__(256, 1) void prep_xw(
    const float* __restrict__ X,            // (T=128, B=1024, M=256) fp32
    const unsigned short* __restrict__ WxF,
    unsigned short* __restrict__ XW,        // (B,T,M) bf16
    unsigned short* __restrict__ Xbf) {     // (B,T,M) bf16
  __shared__ __align__(16) unsigned short XL[128 * 256];
  const int b = blockIdx.x, tid = threadIdx.x;
  for (int i = tid; i < 128 * 256; i += 256) {
    int t = i >> 8, k = i & 255;
    float x = X[(size_t)t * 262144 + (size_t)b * 256 + k];
    unsigned short us = f2bf(x);
    XL[i] = us;
    Xbf[(size_t)b * 32768 + i] = us;
  }
  __syncthreads();
  const int wave = tid >> 6, lane = tid & 63, r = lane & 15, kg = lane >> 4;
  for (int tt = 0; tt < 8; ++tt) {
    uint4 a[8];
#pragma unroll
    for (int ks = 0; ks < 8; ++ks)
      a[ks] = *(const uint4*)&XL[(tt * 16 + r) * 256 + ks * 32 + kg * 8];
#pragma unroll
    for (int mtl = 0; mtl < 4; ++mtl) {
      const int mt = wave * 4 + mtl;
      f32x4 acc = {0.f, 0.f, 0.f, 0.f};
#pragma unroll
      for (int ks = 0; ks < 8; ++ks) {
        uint4 braw = *(const uint4*)(WxF + ((size_t)(mt * 8 + ks) * 64 + lane) * 8);
        acc = __builtin_amdgcn_mfma_f32_16x16x32_bf16(as_s8(a[ks]), as_s8(braw), acc, 0, 0, 0);
      }
      // D: col = lane&15, row = kg*4 + rr
#pragma unroll
      for (int rr = 0; rr < 4; ++rr) {
        int trow = tt * 16 + kg * 4 + rr;
        XW[(size_t)b * 32768 + trow * 256 + mt * 16 + r] = f2bf(acc[rr]);
      }
    }
  }
}

// ---------------- main scan: 1 block = 4 batches, 1 wave = 1 batch ----------------
__global__ __launch_bounds__(256, 1) void scan_k(
    const float* __restrict__ Yg,            // (1024,127,1)
    const unsigned short* __restrict__ XW,   // (B,T,M) bf16
    const unsigned short* __restrict__ Xbf,  // (B,T,M) bf16
    const unsigned short* __restrict__ W1F,
    const unsigned short* __restrict__ W2F,
    const float* __restrict__ bsum,          // 1024
    const float* __restrict__ v_d,           // 256
    const float* __restrict__ Wl,            // 257
    const float* __restrict__ W_ih,          // 1024
    const float* __restrict__ Wb_w,          // 256x512
    const float* __restrict__ Wb_b,          // 256
    const float* __restrict__ vb_w,          // 256
    const float* __restrict__ vb_b,          // 1
    float* __restrict__ outp) {              // 1024
  // hcbf row = batch (rows 4..15 stay zero): [k<256]=h bf16, [256..511]=c bf16
  // stride 520: 16B-aligned rows, banks spread 4(r+kg) -> conflict-free-ish
  __shared__ __align__(16) unsigned short hcbf[16][520];
  __shared__ float dWL[4][256];    // batch-major dW; reused as ctx stash for head
  __shared__ float gL[4][1024];    // gates, batch-major
  __shared__ float cL[4][256];     // fp32 cell state
  __shared__ float lL[4][128];
  __shared__ float betaL[4][128];
  __shared__ float ytL[4];

  const int tid = threadIdx.x;
  const int wave = tid >> 6;
  const int lane = tid & 63;
  const int r = lane & 15;
  const int kg = lane >> 4;
  const int b0 = blockIdx.x * 4;
  const int m4 = lane * 4;

  for (int i = tid; i < 16 * 520; i += 256) (&hcbf[0][0])[i] = 0;
  for (int i = tid; i < 1024; i += 256) (&cL[0][0])[i] = 0.f;

  float v4[4], wl4[4];
#pragma unroll
  for (int i = 0; i < 4; ++i) { v4[i] = v_d[m4 + i]; wl4[i] = Wl[1 + m4 + i]; }
  const float wl0 = Wl[0];
  float wih4[4], bs4[4];
#pragma unroll
  for (int g = 0; g < 4; ++g) { wih4[g] = W_ih[g * 256 + tid]; bs4[g] = bsum[g * 256 + tid]; }

  const unsigned short* XWb = XW + (size_t)(b0 + wave) * (T_SZ * M_SZ);
  const unsigned short* Xb = Xbf + (size_t)(b0 + wave) * (T_SZ * M_SZ);
  const float* Yb = Yg + (size_t)(b0 + wave) * NSTEP;

  float ctx0 = 0.f, ctx1 = 0.f, ctx2 = 0.f, ctx3 = 0.f;

  __syncthreads();

  for (int step = 0; step < NSTEP; ++step) {
    // ---- G1: dW = d @ WU_dd^T via MFMA (A rows = batches 0..3, rest zero) ----
    {
      uint4 a[16];
#pragma unroll
      for (int ks = 0; ks < 16; ++ks)
        a[ks] = *(const uint4*)&hcbf[r][ks * 32 + kg * 8];
#pragma unroll
      for (int mtl = 0; mtl < 4; ++mtl) {
        const int mt = wave * 4 + mtl;
        f32x4 acc = {0.f, 0.f, 0.f, 0.f};
        const unsigned short* bp = W1F + ((size_t)(mt * 16) * 64 + lane) * 8;
#pragma unroll
        for (int ks = 0; ks < 16; ++ks) {
          uint4 braw = *(const uint4*)(bp + (size_t)ks * 512);
          acc = __builtin_amdgcn_mfma_f32_16x16x32_bf16(as_s8(a[ks]), as_s8(braw), acc, 0, 0, 0);
        }
        if (kg == 0) {  // rows 0..3 = batches live in lanes 0..15, regs 0..3
#pragma unroll
          for (int rr = 0; rr < 4; ++rr) dWL[rr][mt * 16 + r] = acc[rr];
        }
      }
    }
    __syncthreads();

    // ---- scores: l[t] = sum_m v[m] * tanh(dW[m] + XW[t][m]) ----
    const float dw0 = dWL[wave][m4], dw1 = dWL[wave][m4 + 1];
    const float dw2 = dWL[wave][m4 + 2], dw3 = dWL[wave][m4 + 3];
#pragma unroll 4
    for (int t = 0; t < T_SZ; ++t) {
      uint2 q = *(const uint2*)&XWb[t * M_SZ + m4];
      float s = v4[0] * tanh_f(dw0 + bf2f_lo(q.x)) + v4[1] * tanh_f(dw1 + bf2f_hi(q.x)) +
                v4[2] * tanh_f(dw2 + bf2f_lo(q.y)) + v4[3] * tanh_f(dw3 + bf2f_hi(q.y));
#pragma unroll
      for (int off = 1; off < 64; off <<= 1) s += __shfl_xor(s, off, 64);
      if (lane == 0) lL[wave][t] = s;
    }
    __syncthreads();

    // ---- softmax over T=128 ----
    {
      float l0 = lL[wave][lane], l1 = lL[wave][64 + lane];
      float mx = fmaxf(l0, l1);
#pragma unroll
      for (int off = 1; off < 64; off <<= 1) mx = fmaxf(mx, __shfl_xor(mx, off, 64));
      float e0 = fexp2((l0 - mx) * 1.4426950408889634f);
      float e1 = fexp2((l1 - mx) * 1.4426950408889634f);
      float sm = e0 + e1;
#pragma unroll
      for (int off = 1; off < 64; off <<= 1) sm += __shfl_xor(sm, off, 64);
      float inv = frcp(sm);
      betaL[wave][lane] = e0 * inv;
      betaL[wave][64 + lane] = e1 * inv;
    }
    __syncthreads();

    // ---- ctx + y_tilde ----
    ctx0 = ctx1 = ctx2 = ctx3 = 0.f;
#pragma unroll 4
    for (int t = 0; t < T_SZ; ++t) {
      float bta = betaL[wave][t];
      uint2 q = *(const uint2*)&Xb[t * M_SZ + m4];
      ctx0 += bta * bf2f_lo(q.x);
      ctx1 += bta * bf2f_hi(q.x);
      ctx2 += bta * bf2f_lo(q.y);
      ctx3 += bta * bf2f_hi(q.y);
    }
    {
      float yt = wl4[0] * ctx0 + wl4[1] * ctx1 + wl4[2] * ctx2 + wl4[3] * ctx3;
#pragma unroll
      for (int off = 1; off < 64; off <<= 1) yt += __shfl_xor(yt, off, 64);
      if (lane == 0) ytL[wave] = yt + wl0 * Yb[step];
    }

    // ---- G2: gates = h @ W_hh^T via MFMA (reads pre-update h; no barrier needed) ----
    {
      uint4 a[8];
#pragma unroll
      for (int ks = 0; ks < 8; ++ks)
        a[ks] = *(const uint4*)&hcbf[r][ks * 32 + kg * 8];
      for (int jtl = 0; jtl < 16; ++jtl) {
        const int jt = wave * 16 + jtl;
        f32x4 acc = {0.f, 0.f, 0.f, 0.f};
        const unsigned short* bp = W2F + ((size_t)(jt * 8) * 64 + lane) * 8;
#pragma unroll
        for (int ks = 0; ks < 8; ++ks) {
          uint4 braw = *(const uint4*)(bp + (size_t)ks * 512);
          acc = __builtin_amdgcn_mfma_f32_16x16x32_bf16(as_s8(a[ks]), as_s8(braw), acc, 0, 0, 0);
        }
        if (kg == 0) {
#pragma unroll
          for (int rr = 0; rr < 4; ++rr) gL[rr][jt * 16 + r] = acc[rr];
        }
      }
    }
    __syncthreads();

    // ---- LSTM update: tid = p, 4 batches each ----
    {
      const int p = tid;
#pragma unroll
      for (int b = 0; b < 4; ++b) {
        float yt = ytL[b];
        float ig = gL[b][p] + yt * wih4[0] + bs4[0];
        float fg = gL[b][256 + p] + yt * wih4[1] + bs4[1];
        float gg = gL[b][512 + p] + yt * wih4[2] + bs4[2];
        float og = gL[b][768 + p] + yt * wih4[3] + bs4[3];
        float cn = sigm_f(fg) * cL[b][p] + sigm_f(ig) * tanh_f(gg);
        float hn = sigm_f(og) * tanh_f(cn);
        cL[b][p] = cn;
        hcbf[b][p] = f2bf(hn);
        hcbf[b][256 + p] = f2bf(cn);
      }
    }
    __syncthreads();
  }

  // ---- output head: out[b] = vb_w . (Wb_w @ [h;ctx] + Wb_b) + vb_b ----
  {
    float cc[4] = {ctx0, ctx1, ctx2, ctx3};
#pragma unroll
    for (int i = 0; i < 4; ++i) dWL[wave][m4 + i] = cc[i];  // stash ctx
  }
  __syncthreads();
  {
    float h0 = 0.f, h1 = 0.f, h2 = 0.f, h3 = 0.f;
    for (int q = 0; q < 512; ++q) {
      float hcq = (q < 256) ? bf2f_lo((unsigned)hcbf[wave][q]) : dWL[wave][q - 256];
      const float* wb = Wb_w + (size_t)m4 * 512 + q;
      h0 += hcq * wb[0];
      h1 += hcq * wb[512];
      h2 += hcq * wb[1024];
      h3 += hcq * wb[1536];
    }
    float o = (h0 + Wb_b[m4]) * vb_w[m4] + (h1 + Wb_b[m4 + 1]) * vb_w[m4 + 1] +
              (h2 + Wb_b[m4 + 2]) * vb_w[m4 + 2] + (h3 + Wb_b[m4 + 3]) * vb_w[m4 + 3];
#pragma unroll
    for (int off = 1; off < 64; off <<= 1) o += __shfl_xor(o, off, 64);
    if (lane == 0) outp[b0 + wave] = o + vb_b[0];
  }
}

extern "C" void kernel_launch(void* const* d_in, const int* in_sizes, int n_in,
                              void* d_out, int out_size, void* d_ws, size_t ws_size,
                              hipStream_t stream) {
  const float* Y = (const float*)d_in[0];
  const float* X = (const float*)d_in[1];
  const float* WU_d = (const float*)d_in[2];
  const float* v_d = (const float*)d_in[3];
  const float* Wl = (const float*)d_in[4];
  const float* W_ih = (const float*)d_in[5];
  const float* W_hh = (const float*)d_in[6];
  const float* b_ih = (const float*)d_in[7];
  const float* b_hh = (const float*)d_in[8];
  const float* Wb_w = (const float*)d_in[9];
  const float* Wb_b = (const float*)d_in[10];
  const float* vb_w = (const float*)d_in[11];
  const float* vb_b = (const float*)d_in[12];

  char* ws = (char*)d_ws;
  unsigned short* XW = (unsigned short*)(ws + 0);            // 64 MB
  unsigned short* Xbf = (unsigned short*)(ws + 67108864);    // 64 MB
  unsigned short* W1F = (unsigned short*)(ws + 134217728);   // 256 KB
  unsigned short* W2F = (unsigned short*)(ws + 134479872);   // 512 KB
  unsigned short* WxF = (unsigned short*)(ws + 135004160);   // 128 KB
  float* bsum = (float*)(ws + 135135232);                    // 4 KB

  prep_w<<<1796, 256, 0, stream>>>(WU_d, W_hh, b_ih, b_hh, W1F, W2F, WxF, bsum);
  prep_xw<<<1024, 256, 0, stream>>>(X, WxF, XW, Xbf);
  scan_k<<<256, 256, 0, stream>>>(Y, XW, Xbf, W1F, W2F, bsum, v_d, Wl, W_ih, Wb_w, Wb_b,
                                  vb_w, vb_b, (float*)d_out);
}

// Round 2
// 6007.803 us; speedup vs baseline: 3.0605x; 3.0605x over previous
//
#include <hip/hip_runtime.h>

// Decoder scan: B=1024, T=128, M=256, P=256, 127 steps.
// R2: 16 waves/block (4 batches x 4 waves/batch) for occupancy+MLP;
// in-loop streaming is XW only (8.3 GB): y_tilde via precomputed XWl,
// full ctx computed once at the final step from fp32 X.

#define B_SZ 1024
#define T_SZ 128
#define M_SZ 256
#define NSTEP 127

typedef __attribute__((ext_vector_type(8))) short short8;
typedef __attribute__((ext_vector_type(4))) float f32x4;

__device__ __forceinline__ float bf2f_lo(unsigned u) {
  return __builtin_bit_cast(float, u << 16);
}
__device__ __forceinline__ float bf2f_hi(unsigned u) {
  return __builtin_bit_cast(float, u & 0xffff0000u);
}
__device__ __forceinline__ unsigned short f2bf(float f) {
  unsigned u = __builtin_bit_cast(unsigned, f);
  u = (u + 0x7fffu + ((u >> 16) & 1u)) >> 16;  // RNE
  return (unsigned short)u;
}
__device__ __forceinline__ float fexp2(float x) { return __builtin_amdgcn_exp2f(x); }
__device__ __forceinline__ float frcp(float x) { return __builtin_amdgcn_rcpf(x); }
__device__ __forceinline__ float tanh_f(float x) {
  float t = fexp2(x * 2.8853900817779268f);
  return 1.f - 2.f * frcp(t + 1.f);
}
__device__ __forceinline__ float sigm_f(float x) {
  return frcp(1.f + fexp2(x * -1.4426950408889634f));
}
__device__ __forceinline__ short8 as_s8(uint4 u) { return __builtin_bit_cast(short8, u); }

// ---------------- prep: weight bf16 fragment swizzles + bias sum ----------------
__global__ void prep_w(const float* __restrict__ WU_d,
                       const float* __restrict__ W_hh,
                       const float* __restrict__ b_ih,
                       const float* __restrict__ b_hh,
                       unsigned short* __restrict__ W1F,
                       unsigned short* __restrict__ W2F,
                       unsigned short* __restrict__ WxF,
                       float* __restrict__ bsum) {
  int i = blockIdx.x * 256 + threadIdx.x;
  if (i < 131072) {
    int j = i & 7, lane = (i >> 3) & 63, ks = (i >> 9) & 15, mt = i >> 13;
    int r = lane & 15, kg = lane >> 4;
    int k = ks * 32 + kg * 8 + j;
    W1F[i] = f2bf(WU_d[(mt * 16 + r) * 768 + k]);
  } else if (i < 131072 + 262144) {
    int i2 = i - 131072;
    int j = i2 & 7, lane = (i2 >> 3) & 63, ks = (i2 >> 9) & 7, jt = i2 >> 12;
    int r = lane & 15, kg = lane >> 4;
    int k = ks * 32 + kg * 8 + j;
    W2F[i2] = f2bf(W_hh[(jt * 16 + r) * 256 + k]);
  } else if (i < 131072 + 262144 + 65536) {
    int i3 = i - (131072 + 262144);
    int j = i3 & 7, lane = (i3 >> 3) & 63, ks = (i3 >> 9) & 7, mt = i3 >> 12;
    int r = lane & 15, kg = lane >> 4;
    int k = 512 + ks * 32 + kg * 8 + j;
    WxF[i3] = f2bf(WU_d[(mt * 16 + r) * 768 + k]);
  } else if (i < 131072 + 262144 + 65536 + 1024) {
    int i4 = i - (131072 + 262144 + 65536);
    bsum[i4] = b_ih[i4] + b_hh[i4];
  }
}

// ---------------- prep: XW = X @ WU_dx^T (bf16) and XWl[b][t] = Wl[1:].X[b][t] ----------------
__global__ __launch_bounds__(256, 1) void prep_xw(
    const float* __restrict__ X,            // (T=128, B=1024, M=256) fp32
    const unsigned short* __restrict__ WxF,
    const float* __restrict__ Wl,           // 257
    unsigned short* __restrict__ XW,        // (B,T,M) bf16
    float* __restrict__ XWl) {              // (B,T) fp32
  __shared__ __align__(16) unsigned short XL[128 * 256];
  const int b = blockIdx.x, tid = threadIdx.x;
  for (int i = tid; i < 128 * 256; i += 256) {
    int t = i >> 8, k = i & 255;
    XL[i] = f2bf(X[(size_t)t * 262144 + (size_t)b * 256 + k]);
  }
  __syncthreads();
  const int wave = tid >> 6, lane = tid & 63, r = lane & 15, kg = lane >> 4;
  for (int tt = 0; tt < 8; ++tt) {
    uint4 a[8];
#pragma unroll
    for (int ks = 0; ks < 8; ++ks)
      a[ks] = *(const uint4*)&XL[(tt * 16 + r) * 256 + ks * 32 + kg * 8];
#pragma unroll
    for (int mtl = 0; mtl < 4; ++mtl) {
      const int mt = wave * 4 + mtl;
      f32x4 acc = {0.f, 0.f, 0.f, 0.f};
#pragma unroll
      for (int ks = 0; ks < 8; ++ks) {
        uint4 braw = *(const uint4*)(WxF + ((size_t)(mt * 8 + ks) * 64 + lane) * 8);
        acc = __builtin_amdgcn_mfma_f32_16x16x32_bf16(as_s8(a[ks]), as_s8(braw), acc, 0, 0, 0);
      }
#pragma unroll
      for (int rr = 0; rr < 4; ++rr) {
        int trow = tt * 16 + kg * 4 + rr;
        XW[(size_t)b * 32768 + trow * 256 + mt * 16 + r] = f2bf(acc[rr]);
      }
    }
  }
  // XWl: wave handles t in [wave*32, wave*32+32)
  float wl4[4];
#pragma unroll
  for (int j = 0; j < 4; ++j) wl4[j] = Wl[1 + lane * 4 + j];
  for (int t = wave * 32; t < wave * 32 + 32; ++t) {
    uint2 q = *(const uint2*)&XL[t * 256 + lane * 4];
    float s = wl4[0] * bf2f_lo(q.x) + wl4[1] * bf2f_hi(q.x) +
              wl4[2] * bf2f_lo(q.y) + wl4[3] * bf2f_hi(q.y);
#pragma unroll
    for (int off = 1; off < 64; off <<= 1) s += __shfl_xor(s, off, 64);
    if (lane == 0) XWl[b * 128 + t] = s;
  }
}

// ---------------- main scan: 1 block = 1024 thr = 16 waves = 4 batches x 4 waves ----------------
__global__ __launch_bounds__(1024, 4) void scan_k(
    const float* __restrict__ Yg,            // (1024,127,1)
    const float* __restrict__ X,             // (T,B,M) fp32 (final ctx only)
    const unsigned short* __restrict__ XW,   // (B,T,M) bf16
    const float* __restrict__ XWl,           // (B,T) fp32
    const unsigned short* __restrict__ W1F,
    const unsigned short* __restrict__ W2F,
    const float* __restrict__ bsum,          // 1024
    const float* __restrict__ v_d,           // 256
    const float* __restrict__ Wl,            // 257
    const float* __restrict__ W_ih,          // 1024
    const float* __restrict__ Wb_w,          // 256x512
    const float* __restrict__ Wb_b,          // 256
    const float* __restrict__ vb_w,          // 256
    const float* __restrict__ vb_b,          // 1
    float* __restrict__ outp) {              // 1024
  __shared__ __align__(16) unsigned short hcbf[16][520];  // [b][0:256)=h bf16, [256:512)=c bf16
  __shared__ __align__(16) float dWL[4][256];
  __shared__ float gL[4][1024];
  __shared__ float lL[4][128];
  __shared__ float betaL[4][128];
  __shared__ float ctxW[4][4][256];
  __shared__ float ctxL[4][256];
  __shared__ float ytL[4];

  const int tid = threadIdx.x;
  const int wave = tid >> 6;
  const int lane = tid & 63;
  const int r = lane & 15;
  const int kg = lane >> 4;
  const int b0 = blockIdx.x * 4;
  const int bb = wave >> 2;        // batch of this wave (0..3)
  const int tw = wave & 3;         // t-chunk of this wave (0..3)
  const int lp = tid & 255;        // LSTM p-index
  const int lb = tid >> 8;         // LSTM batch
  const int m8 = (lane & 31) * 8;  // score-pass m offset (8 bf16)
  const int th = lane >> 5;        // score-pass t parity

  for (int i = tid; i < 16 * 520; i += 1024) (&hcbf[0][0])[i] = 0;

  // per-lane preloads
  float v8[8];
#pragma unroll
  for (int j = 0; j < 8; ++j) v8[j] = v_d[m8 + j];
  float wih4g[4], bs4g[4];
#pragma unroll
  for (int g = 0; g < 4; ++g) { wih4g[g] = W_ih[g * 256 + lp]; bs4g[g] = bsum[g * 256 + lp]; }
  const float wl0 = Wl[0];
  float c_reg = 0.f;  // cell state for (lb, lp)

  const unsigned short* XWb = XW + (size_t)(b0 + bb) * (T_SZ * M_SZ);
  const float* Yb = Yg + (size_t)(b0 + wave) * NSTEP;  // only waves 0..3 use
  const float* XWlb = XWl + (size_t)(b0 + wave) * T_SZ;

  __syncthreads();

  for (int step = 0; step < NSTEP; ++step) {
    // ---- G1: dW = d @ WU_dd^T; wave = mt tile (16 waves x 16 m each) ----
    {
      const int mt = wave;
      f32x4 acc = {0.f, 0.f, 0.f, 0.f};
      const unsigned short* bp = W1F + ((size_t)(mt * 16) * 64 + lane) * 8;
#pragma unroll
      for (int ks = 0; ks < 16; ++ks) {
        uint4 a = *(const uint4*)&hcbf[r][ks * 32 + kg * 8];
        uint4 braw = *(const uint4*)(bp + (size_t)ks * 512);
        acc = __builtin_amdgcn_mfma_f32_16x16x32_bf16(as_s8(a), as_s8(braw), acc, 0, 0, 0);
      }
      if (kg == 0) {
#pragma unroll
        for (int rr = 0; rr < 4; ++rr) dWL[rr][mt * 16 + r] = acc[rr];
      }
    }
    __syncthreads();

    // ---- scores: wave (bb,tw) covers t in [tw*32, tw*32+32), lane covers 8 m ----
    {
      float dw8[8];
      *(f32x4*)&dw8[0] = *(const f32x4*)&dWL[bb][m8];
      *(f32x4*)&dw8[4] = *(const f32x4*)&dWL[bb][m8 + 4];
      const unsigned short* p = XWb + (tw * 32 + th) * M_SZ + m8;
#pragma unroll 8
      for (int i = 0; i < 16; ++i) {
        uint4 q = *(const uint4*)(p + i * 512);
        float s = v8[0] * tanh_f(dw8[0] + bf2f_lo(q.x)) + v8[1] * tanh_f(dw8[1] + bf2f_hi(q.x)) +
                  v8[2] * tanh_f(dw8[2] + bf2f_lo(q.y)) + v8[3] * tanh_f(dw8[3] + bf2f_hi(q.y)) +
                  v8[4] * tanh_f(dw8[4] + bf2f_lo(q.z)) + v8[5] * tanh_f(dw8[5] + bf2f_hi(q.z)) +
                  v8[6] * tanh_f(dw8[6] + bf2f_lo(q.w)) + v8[7] * tanh_f(dw8[7] + bf2f_hi(q.w));
#pragma unroll
        for (int off = 1; off < 32; off <<= 1) s += __shfl_xor(s, off, 64);
        if ((lane & 31) == 0) lL[bb][tw * 32 + 2 * i + th] = s;
      }
    }
    __syncthreads();

    // ---- softmax + y_tilde (waves 0..3, batch = wave) ----
    if (wave < 4) {
      float l0 = lL[wave][lane], l1 = lL[wave][64 + lane];
      float mx = fmaxf(l0, l1);
#pragma unroll
      for (int off = 1; off < 64; off <<= 1) mx = fmaxf(mx, __shfl_xor(mx, off, 64));
      float e0 = fexp2((l0 - mx) * 1.4426950408889634f);
      float e1 = fexp2((l1 - mx) * 1.4426950408889634f);
      float sm = e0 + e1;
      float yt = e0 * XWlb[lane] + e1 * XWlb[64 + lane];
#pragma unroll
      for (int off = 1; off < 64; off <<= 1) {
        sm += __shfl_xor(sm, off, 64);
        yt += __shfl_xor(yt, off, 64);
      }
      float inv = frcp(sm);
      betaL[wave][lane] = e0 * inv;
      betaL[wave][64 + lane] = e1 * inv;
      if (lane == 0) ytL[wave] = yt * inv + wl0 * Yb[step];
    }

    // ---- G2: gates = h @ W_hh^T; wave handles 4 jt tiles ----
    {
#pragma unroll
      for (int jtl = 0; jtl < 4; ++jtl) {
        const int jt = wave * 4 + jtl;
        f32x4 acc = {0.f, 0.f, 0.f, 0.f};
        const unsigned short* bp = W2F + ((size_t)(jt * 8) * 64 + lane) * 8;
#pragma unroll
        for (int ks = 0; ks < 8; ++ks) {
          uint4 a = *(const uint4*)&hcbf[r][ks * 32 + kg * 8];
          uint4 braw = *(const uint4*)(bp + (size_t)ks * 512);
          acc = __builtin_amdgcn_mfma_f32_16x16x32_bf16(as_s8(a), as_s8(braw), acc, 0, 0, 0);
        }
        if (kg == 0) {
#pragma unroll
          for (int rr = 0; rr < 4; ++rr) gL[rr][jt * 16 + r] = acc[rr];
        }
      }
    }
    __syncthreads();

    // ---- final-step ctx partials (needs betaL) ----
    if (step == NSTEP - 1) {
      const int m4 = lane * 4;
      f32x4 c4 = {0.f, 0.f, 0.f, 0.f};
      for (int t = tw * 32; t < tw * 32 + 32; ++t) {
        float bta = betaL[bb][t];
        f32x4 x4 = *(const f32x4*)&X[(size_t)t * 262144 + (size_t)(b0 + bb) * 256 + m4];
        c4.x += bta * x4.x;
        c4.y += bta * x4.y;
        c4.z += bta * x4.z;
        c4.w += bta * x4.w;
      }
      *(f32x4*)&ctxW[bb][tw][m4] = c4;
    }

    // ---- LSTM update: thread = (lb, lp) ----
    {
      float yt = ytL[lb];
      float ig = gL[lb][lp] + yt * wih4g[0] + bs4g[0];
      float fg = gL[lb][256 + lp] + yt * wih4g[1] + bs4g[1];
      float gg = gL[lb][512 + lp] + yt * wih4g[2] + bs4g[2];
      float og = gL[lb][768 + lp] + yt * wih4g[3] + bs4g[3];
      float cn = sigm_f(fg) * c_reg + sigm_f(ig) * tanh_f(gg);
      float hn = sigm_f(og) * tanh_f(cn);
      c_reg = cn;
      hcbf[lb][lp] = f2bf(hn);
      hcbf[lb][256 + lp] = f2bf(cn);
    }
    __syncthreads();
  }

  // ---- reduce ctx partials ----
  ctxL[lb][lp] = ctxW[lb][0][lp] + ctxW[lb][1][lp] + ctxW[lb][2][lp] + ctxW[lb][3][lp];
  __syncthreads();

  // ---- output head: waves 0..3, batch = wave ----
  if (wave < 4) {
    const int m4 = lane * 4;
    float h0 = 0.f, h1 = 0.f, h2 = 0.f, h3 = 0.f;
    for (int q = 0; q < 512; ++q) {
      float hcq = (q < 256) ? bf2f_lo((unsigned)hcbf[wave][q]) : ctxL[wave][q - 256];
      const float* wb = Wb_w + (size_t)m4 * 512 + q;
      h0 += hcq * wb[0];
      h1 += hcq * wb[512];
      h2 += hcq * wb[1024];
      h3 += hcq * wb[1536];
    }
    float o = (h0 + Wb_b[m4]) * vb_w[m4] + (h1 + Wb_b[m4 + 1]) * vb_w[m4 + 1] +
              (h2 + Wb_b[m4 + 2]) * vb_w[m4 + 2] + (h3 + Wb_b[m4 + 3]) * vb_w[m4 + 3];
#pragma unroll
    for (int off = 1; off < 64; off <<= 1) o += __shfl_xor(o, off, 64);
    if (lane == 0) outp[b0 + wave] = o + vb_b[0];
  }
}

extern "C" void kernel_launch(void* const* d_in, const int* in_sizes, int n_in,
                              void* d_out, int out_size, void* d_ws, size_t ws_size,
                              hipStream_t stream) {
  const float* Y = (const float*)d_in[0];
  const float* X = (const float*)d_in[1];
  const float* WU_d = (const float*)d_in[2];
  const float* v_d = (const float*)d_in[3];
  const float* Wl = (const float*)d_in[4];
  const float* W_ih = (const float*)d_in[5];
  const float* W_hh = (const float*)d_in[6];
  const float* b_ih = (const float*)d_in[7];
  const float* b_hh = (const float*)d_in[8];
  const float* Wb_w = (const float*)d_in[9];
  const float* Wb_b = (const float*)d_in[10];
  const float* vb_w = (const float*)d_in[11];
  const float* vb_b = (const float*)d_in[12];

  char* ws = (char*)d_ws;
  unsigned short* XW = (unsigned short*)(ws + 0);            // 64 MB
  float* XWl = (float*)(ws + 67108864);                      // 512 KB
  unsigned short* W1F = (unsigned short*)(ws + 67633152);    // 256 KB
  unsigned short* W2F = (unsigned short*)(ws + 67895296);    // 512 KB
  unsigned short* WxF = (unsigned short*)(ws + 68419584);    // 128 KB
  float* bsum = (float*)(ws + 68550656);                     // 4 KB

  prep_w<<<1796, 256, 0, stream>>>(WU_d, W_hh, b_ih, b_hh, W1F, W2F, WxF, bsum);
  prep_xw<<<1024, 256, 0, stream>>>(X, WxF, Wl, XW, XWl);
  scan_k<<<256, 1024, 0, stream>>>(Y, X, XW, XWl, W1F, W2F, bsum, v_d, Wl, W_ih,
                                   Wb_w, Wb_b, vb_w, vb_b, (float*)d_out);
}